// Round 7
// baseline (713.033 us; speedup 1.0000x reference)
//
#include <hip/hip_runtime.h>

// ---------------------------------------------------------------------------
// RelPositionMultiHeadedAttention (Conformer / Transformer-XL rel-shift)
// B=4, T=2048, C=512, H=8, D=64
//
// R7 changes:
//  - attn: ALL MFMA operands loaded directly from global (16B contiguous per
//    lane). V stored transposed VT[bh][d][t] by the projection kernel.
//    k_s/vT_s/pA LDS regions and ALL __syncthreads deleted; LDS = msw only
//    (11264 B). Occupancy now VGPR-limited: __launch_bounds__(256,4).
//  - split_gemm: z==2 epilogue writes VT (scattered 2B stores; L2 coalesces).
// ---------------------------------------------------------------------------

#define Bb 4
#define Tt 2048
#define Cc 512
#define Hh 8
#define Dd 64

typedef __bf16 bf16_t;
typedef __bf16 bf16x8 __attribute__((ext_vector_type(8)));
typedef float  f32x4  __attribute__((ext_vector_type(4)));

// ---------------------------------------------------------------------------
// Split-bf16 MFMA GEMM: Y = X @ W (+bias). X [8192,512] fp32, W [512,512] fp32.
// mode (modeArg<0 ? blockIdx.z : modeArg): 0=Q(->QU,QV) 1=K 2=V(->VT) 3=P 4=out.
// ---------------------------------------------------------------------------
__global__ __launch_bounds__(256, 2)
void split_gemm_kernel(const float* __restrict__ Xq, const float* __restrict__ Xk,
                       const float* __restrict__ Xv, const float* __restrict__ Xp,
                       const float* __restrict__ Xc,
                       const float* __restrict__ Wq, const float* __restrict__ Wk,
                       const float* __restrict__ Wv, const float* __restrict__ Wp,
                       const float* __restrict__ Wo,
                       const float* __restrict__ bq, const float* __restrict__ bk,
                       const float* __restrict__ bv, const float* __restrict__ bo,
                       const float* __restrict__ bias_u, const float* __restrict__ bias_v,
                       bf16_t* __restrict__ QU, bf16_t* __restrict__ QV,
                       bf16_t* __restrict__ K16, bf16_t* __restrict__ VT16,
                       bf16_t* __restrict__ P16, float* __restrict__ OUT,
                       int modeArg)
{
    const int z = (modeArg < 0) ? blockIdx.z : modeArg;
    const float* X    = (z == 0) ? Xq : (z == 1) ? Xk : (z == 2) ? Xv : (z == 3) ? Xp : Xc;
    const float* W    = (z == 0) ? Wq : (z == 1) ? Wk : (z == 2) ? Wv : (z == 3) ? Wp : Wo;
    const float* bias = (z == 0) ? bq : (z == 1) ? bk : (z == 2) ? bv : (z == 3) ? nullptr : bo;

    const int bx = blockIdx.x;
    const int g  = bx >> 3, x8 = bx & 7;
    const int mtile = (g >> 2) * 8 + x8;   // 0..63
    const int ntile = g & 3;               // 0..3
    const int r0 = mtile * 128;
    const int c0 = ntile * 128;

    const int tid  = threadIdx.x;
    const int wave = tid >> 6;
    const int lane = tid & 63;
    const int quad = lane >> 4;
    const int l16  = lane & 15;
    const int rb = (wave >> 1) * 64;
    const int cb = (wave & 1) * 64;

    __shared__ __align__(16) float Xs[128][68];
    __shared__ float Wt[128][65];

    f32x4 acc[4][4];
#pragma unroll
    for (int mt = 0; mt < 4; mt++)
#pragma unroll
        for (int nt = 0; nt < 4; nt++)
#pragma unroll
            for (int r = 0; r < 4; r++) acc[mt][nt][r] = 0.f;

    for (int it = 0; it < 8; ++it) {
        const int k0 = it * 64;
#pragma unroll
        for (int rep = 0; rep < 8; rep++) {
            int id = rep * 256 + tid;
            int m = id >> 4, c = id & 15;
            f32x4 v = *(const f32x4*)&X[(size_t)(r0 + m) * 512 + k0 + c * 4];
            *(f32x4*)&Xs[m][c * 4] = v;
        }
#pragma unroll
        for (int rep = 0; rep < 8; rep++) {
            int id = rep * 256 + tid;
            int cc = id & 31, kk = id >> 5;
            f32x4 v = *(const f32x4*)&W[(size_t)(k0 + kk) * 512 + c0 + cc * 4];
#pragma unroll
            for (int i = 0; i < 4; i++) Wt[cc * 4 + i][kk] = v[i];
        }
        __syncthreads();

#pragma unroll
        for (int kc = 0; kc < 2; kc++) {
            bf16x8 Bhi[4], Blo[4];
#pragma unroll
            for (int nt = 0; nt < 4; nt++) {
#pragma unroll
                for (int e = 0; e < 8; e++) {
                    float f = Wt[cb + nt * 16 + l16][kc * 32 + quad * 8 + e];
                    bf16_t hi = (bf16_t)f;
                    Bhi[nt][e] = hi;
                    Blo[nt][e] = (bf16_t)(f - (float)hi);
                }
            }
#pragma unroll
            for (int mt = 0; mt < 4; mt++) {
                f32x4 a0 = *(const f32x4*)&Xs[rb + mt * 16 + l16][kc * 32 + quad * 8];
                f32x4 a1 = *(const f32x4*)&Xs[rb + mt * 16 + l16][kc * 32 + quad * 8 + 4];
                bf16x8 Ahi, Alo;
#pragma unroll
                for (int e = 0; e < 4; e++) {
                    bf16_t h0 = (bf16_t)a0[e];
                    Ahi[e] = h0; Alo[e] = (bf16_t)(a0[e] - (float)h0);
                    bf16_t h1 = (bf16_t)a1[e];
                    Ahi[4 + e] = h1; Alo[4 + e] = (bf16_t)(a1[e] - (float)h1);
                }
#pragma unroll
                for (int nt = 0; nt < 4; nt++) {
                    acc[mt][nt] = __builtin_amdgcn_mfma_f32_16x16x32_bf16(Ahi, Bhi[nt], acc[mt][nt], 0, 0, 0);
                    acc[mt][nt] = __builtin_amdgcn_mfma_f32_16x16x32_bf16(Ahi, Blo[nt], acc[mt][nt], 0, 0, 0);
                    acc[mt][nt] = __builtin_amdgcn_mfma_f32_16x16x32_bf16(Alo, Bhi[nt], acc[mt][nt], 0, 0, 0);
                }
            }
        }
        __syncthreads();
    }

#pragma unroll
    for (int mt = 0; mt < 4; mt++) {
#pragma unroll
        for (int r = 0; r < 4; r++) {
            int row = r0 + rb + mt * 16 + quad * 4 + r;
#pragma unroll
            for (int nt = 0; nt < 4; nt++) {
                int col = c0 + cb + nt * 16 + l16;
                float y = acc[mt][nt][r] + (bias ? bias[col] : 0.f);
                if (z == 4) {
                    OUT[(size_t)row * 512 + col] = y;
                } else {
                    int b = row >> 11, t = row & 2047;
                    int h = col >> 6,  d = col & 63;
                    if (z == 0) {
                        size_t idx = (((size_t)(b * Hh + h)) * Tt + t) * Dd + d;
                        QU[idx] = (bf16_t)(y + bias_u[col]);
                        QV[idx] = (bf16_t)(y + bias_v[col]);
                    } else if (z == 1) {
                        size_t idx = (((size_t)(b * Hh + h)) * Tt + t) * Dd + d;
                        K16[idx] = (bf16_t)y;
                    } else if (z == 2) {
                        // transposed: VT[bh][d][t]
                        size_t idx = (((size_t)(b * Hh + h)) * Dd + d) * Tt + t;
                        VT16[idx] = (bf16_t)y;
                    } else {
                        size_t idx = (((size_t)(b * Hh + h)) * Tt + t) * Dd + d;
                        P16[idx] = (bf16_t)y;
                    }
                }
            }
        }
    }
}

// ---------------------------------------------------------------------------
// Kernel 2: attention. grid = (bh=32, itile=32); same-bh blocks share an XCD.
// NO __syncthreads anywhere. All MFMA operands are direct global 16B loads.
// LDS: msw [64][88] bf16 only (11264 B), wave-private strips, STRIP-LOCAL
// skewed pos scores (col' = jl + 15 - (il - wave*16), window [0,78]);
// softmax weights later clobber cols 0..63 (strictly after the gathers).
// ---------------------------------------------------------------------------
__global__ __launch_bounds__(256, 4)
void attn_kernel(const bf16_t* __restrict__ QU, const bf16_t* __restrict__ QV,
                 const bf16_t* __restrict__ K16, const bf16_t* __restrict__ VT16,
                 const bf16_t* __restrict__ P16, float* __restrict__ CTX)
{
    const int bh = blockIdx.x;                 // XCD locality: linear%8 = bh%8
    const int i0 = blockIdx.y * 64;
    const int b = bh >> 3, h = bh & 7;
    const int tid = threadIdx.x;
    const int wave = tid >> 6;
    const int lane = tid & 63;
    const int quad = lane >> 4;
    const int l16 = lane & 15;

    const bf16_t* qu_g = QU + (size_t)bh * Tt * Dd;
    const bf16_t* qv_g = QV + (size_t)bh * Tt * Dd;
    const bf16_t* k_g  = K16 + (size_t)bh * Tt * Dd;
    const bf16_t* vt_g = VT16 + (size_t)bh * Dd * Tt;   // [d][t]
    const bf16_t* p_g  = P16 + (size_t)bh * Tt * Dd;

    __shared__ bf16_t msw[64][88];             // strip-local skew buffer

    const int off_w = 48 - wave * 16;          // strip-local = absolute - off_w
    const int cmin = 48 - wave * 16;           // absolute strip window
    const int cmax = 126 - wave * 16;

    // A-operand fragments, direct global loads: A[m=l16][k=quad*8+e]
    const int qrow = i0 + wave * 16 + l16;
    const int qrow2 = (qrow + 1 > Tt - 1) ? (Tt - 1) : (qrow + 1);  // never gathered when clamped
    bf16x8 aq[2], av1[2], av2[2];
#pragma unroll
    for (int kc = 0; kc < 2; kc++) {
        aq[kc]  = *(const bf16x8*)(qu_g + (size_t)qrow  * Dd + kc * 32 + quad * 8);
        av1[kc] = *(const bf16x8*)(qv_g + (size_t)qrow  * Dd + kc * 32 + quad * 8);
        av2[kc] = *(const bf16x8*)(qv_g + (size_t)qrow2 * Dd + kc * 32 + quad * 8);
    }

    float lsum[4];
    f32x4 accO[4];
#pragma unroll
    for (int r = 0; r < 4; r++) lsum[r] = 0.f;
#pragma unroll
    for (int dt = 0; dt < 4; dt++)
#pragma unroll
        for (int r = 0; r < 4; r++) accO[dt][r] = 0.f;

    for (int j0 = 0; j0 < Tt; j0 += 64) {
        int d_lo = i0 - (j0 + 63);
        int d_hi = i0 + 63 - j0;
        int w1 = 0, prow1 = 0;
        if (d_hi >= 0) {
            int b1 = d_lo > 0 ? d_lo : 0;
            w1 = d_hi - b1 + 1;
            prow1 = (Tt - 1) - d_hi;
        }
        int dmax2 = d_hi < -2 ? d_hi : -2;
        int w2 = 0, e_lo = 0;
        if (d_lo <= dmax2) {
            e_lo = -dmax2 - 2;
            int e_hi = -d_lo - 2;
            w2 = e_hi - e_lo + 1;
        }
        int c2_0 = d_hi + 2 + e_lo;
        int nct1 = (w1 + 15) >> 4;
        int nct2 = (w2 + 15) >> 4;

        // content scores: B-frag direct from K16 (identical values to staged)
        f32x4 accS[4];
#pragma unroll
        for (int nt = 0; nt < 4; nt++) {
            f32x4 acc = {0.f, 0.f, 0.f, 0.f};
#pragma unroll
            for (int kc = 0; kc < 2; kc++) {
                bf16x8 bk8 = *(const bf16x8*)(k_g + (size_t)(j0 + nt * 16 + l16) * Dd + kc * 32 + quad * 8);
                acc = __builtin_amdgcn_mfma_f32_16x16x32_bf16(aq[kc], bk8, acc, 0, 0, 0);
            }
            accS[nt] = acc;
        }

        // banded pos matmul -> strip-local skewed store (wave-private).
        // B-frag direct from P16; pad rows clamped (garbage lands in cols
        // that are never gathered or are overwritten before the gather).
        for (int ct = 0; ct < nct1 + nct2; ct++) {
            bool b2 = ct >= nct1;
            int cb_ = b2 ? (c2_0 + (ct - nct1) * 16) : (ct * 16);
            if (cb_ > cmax || cb_ + 15 < cmin) continue;
            int srcrow = (b2 ? (e_lo + (ct - nct1) * 16) : (prow1 + ct * 16)) + l16;
            if (srcrow > Tt - 1) srcrow = Tt - 1;
            f32x4 acc = {0.f, 0.f, 0.f, 0.f};
#pragma unroll
            for (int kc = 0; kc < 2; kc++) {
                bf16x8 bp = *(const bf16x8*)(p_g + (size_t)srcrow * Dd + kc * 32 + quad * 8);
                acc = b2 ? __builtin_amdgcn_mfma_f32_16x16x32_bf16(av2[kc], bp, acc, 0, 0, 0)
                         : __builtin_amdgcn_mfma_f32_16x16x32_bf16(av1[kc], bp, acc, 0, 0, 0);
            }
            int colp = cb_ + l16 - off_w;          // strip-local
            if ((unsigned)colp < 80u) {
#pragma unroll
                for (int r = 0; r < 4; r++)
                    msw[wave * 16 + quad * 4 + r][colp] = (bf16_t)acc[r];
            }
        }
        // zero column for dd == -1 (strip-local)
        {
            int zcl = d_hi + 1 - off_w;
            if ((unsigned)zcl < 80u && quad == 0)
                msw[wave * 16 + l16][zcl] = (bf16_t)0.f;
        }

        // gather all 16 (no aliasing stores in between), then write weights
        float wv[4][4];
#pragma unroll
        for (int nt = 0; nt < 4; nt++) {
#pragma unroll
            for (int r = 0; r < 4; r++) {
                float pos = (float)msw[wave * 16 + quad * 4 + r]
                                    [nt * 16 + l16 + 15 - (quad * 4 + r)];
                float x = accS[nt][r] + pos;
                float a = fminf(fmaf(x, 0.18033688f, -17.3123405f), 120.0f);
                float w = exp2f(a);
                lsum[r] += w;
                wv[nt][r] = w;
            }
        }
#pragma unroll
        for (int nt = 0; nt < 4; nt++)
#pragma unroll
            for (int r = 0; r < 4; r++)
                msw[wave * 16 + quad * 4 + r][nt * 16 + l16] = (bf16_t)wv[nt][r];

        // O += W @ V : A from own msw strip, B direct from VT ([d][t])
#pragma unroll
        for (int kc = 0; kc < 2; kc++) {
            bf16x8 aw = *(const bf16x8*)&msw[wave * 16 + l16][kc * 32 + quad * 8];
#pragma unroll
            for (int dt = 0; dt < 4; dt++) {
                bf16x8 bv8 = *(const bf16x8*)(vt_g + (size_t)(dt * 16 + l16) * Tt + j0 + kc * 32 + quad * 8);
                accO[dt] = __builtin_amdgcn_mfma_f32_16x16x32_bf16(aw, bv8, accO[dt], 0, 0, 0);
            }
        }
    }

#pragma unroll
    for (int r = 0; r < 4; r++) {
#pragma unroll
        for (int off = 1; off < 16; off <<= 1) lsum[r] += __shfl_xor(lsum[r], off, 64);
    }

#pragma unroll
    for (int r = 0; r < 4; r++) {
        int il = wave * 16 + quad * 4 + r;
        int ig = i0 + il;
        float inv = 1.0f / lsum[r];
#pragma unroll
        for (int dt = 0; dt < 4; dt++) {
            CTX[((size_t)(b * Tt + ig)) * Cc + h * Dd + dt * 16 + l16] = accO[dt][r] * inv;
        }
    }
}

// ---------------------------------------------------------------------------
extern "C" void kernel_launch(void* const* d_in, const int* in_sizes, int n_in,
                              void* d_out, int out_size, void* d_ws, size_t ws_size,
                              hipStream_t stream)
{
    const float* query = (const float*)d_in[0];
    const float* key   = (const float*)d_in[1];
    const float* value = (const float*)d_in[2];
    const float* pemb  = (const float*)d_in[3];
    const float* Wq    = (const float*)d_in[4];
    const float* bq    = (const float*)d_in[5];
    const float* Wk    = (const float*)d_in[6];
    const float* bk    = (const float*)d_in[7];
    const float* Wv    = (const float*)d_in[8];
    const float* bv    = (const float*)d_in[9];
    const float* Wpos  = (const float*)d_in[10];
    const float* pbu   = (const float*)d_in[11];
    const float* pbv   = (const float*)d_in[12];
    const float* Wo    = (const float*)d_in[13];
    const float* bo    = (const float*)d_in[14];

    const size_t NE = (size_t)Bb * Hh * Tt * Dd;  // 4,194,304 per tensor
    bf16_t* QU   = (bf16_t*)d_ws;
    bf16_t* QV   = QU + NE;
    bf16_t* K16  = QV + NE;
    bf16_t* VT16 = K16 + NE;
    bf16_t* P16  = VT16 + NE;
    float*  CTX  = (float*)(P16 + NE);            // ws >= 56 MB

    // QKVP projections (z = blockIdx.z)
    split_gemm_kernel<<<dim3(256, 1, 4), 256, 0, stream>>>(
        query, key, value, pemb, CTX, Wq, Wk, Wv, Wpos, Wo,
        bq, bk, bv, bo, pbu, pbv, QU, QV, K16, VT16, P16, (float*)d_out, -1);

    attn_kernel<<<dim3(32, 32), 256, 0, stream>>>(QU, QV, K16, VT16, P16, CTX);

    // output projection (mode 4)
    split_gemm_kernel<<<dim3(256, 1, 1), 256, 0, stream>>>(
        query, key, value, pemb, CTX, Wq, Wk, Wv, Wpos, Wo,
        bq, bk, bv, bo, pbu, pbv, QU, QV, K16, VT16, P16, (float*)d_out, 4);
}

// Round 8
// 549.148 us; speedup vs baseline: 1.2984x; 1.2984x over previous
//
#include <hip/hip_runtime.h>

// ---------------------------------------------------------------------------
// RelPositionMultiHeadedAttention (Conformer / Transformer-XL rel-shift)
// B=4, T=2048, C=512, H=8, D=64
//
// R8 = R6/R7 hybrid (attn):
//  - K tile + P band staged in LDS (high-reuse, 4x per block) as in R6.
//  - V direct from global via VT[bh][d][t] (8 loads/wave/j-tile) as in R7;
//    vT_s region + transpose scatter (the main conflict source) deleted.
//  - Q A-frags loaded direct from global in preamble (pA is P-band only).
//  - LDS 38912 B => 3 blocks/CU under the ~128KB schedulable pool.
// ---------------------------------------------------------------------------

#define Bb 4
#define Tt 2048
#define Cc 512
#define Hh 8
#define Dd 64

typedef __bf16 bf16_t;
typedef __bf16 bf16x8 __attribute__((ext_vector_type(8)));
typedef float  f32x4  __attribute__((ext_vector_type(4)));

// ---------------------------------------------------------------------------
// Split-bf16 MFMA GEMM: Y = X @ W (+bias). X [8192,512] fp32, W [512,512] fp32.
// mode (modeArg<0 ? blockIdx.z : modeArg): 0=Q(->QU,QV) 1=K 2=V(->VT) 3=P 4=out.
// ---------------------------------------------------------------------------
__global__ __launch_bounds__(256, 2)
void split_gemm_kernel(const float* __restrict__ Xq, const float* __restrict__ Xk,
                       const float* __restrict__ Xv, const float* __restrict__ Xp,
                       const float* __restrict__ Xc,
                       const float* __restrict__ Wq, const float* __restrict__ Wk,
                       const float* __restrict__ Wv, const float* __restrict__ Wp,
                       const float* __restrict__ Wo,
                       const float* __restrict__ bq, const float* __restrict__ bk,
                       const float* __restrict__ bv, const float* __restrict__ bo,
                       const float* __restrict__ bias_u, const float* __restrict__ bias_v,
                       bf16_t* __restrict__ QU, bf16_t* __restrict__ QV,
                       bf16_t* __restrict__ K16, bf16_t* __restrict__ VT16,
                       bf16_t* __restrict__ P16, float* __restrict__ OUT,
                       int modeArg)
{
    const int z = (modeArg < 0) ? blockIdx.z : modeArg;
    const float* X    = (z == 0) ? Xq : (z == 1) ? Xk : (z == 2) ? Xv : (z == 3) ? Xp : Xc;
    const float* W    = (z == 0) ? Wq : (z == 1) ? Wk : (z == 2) ? Wv : (z == 3) ? Wp : Wo;
    const float* bias = (z == 0) ? bq : (z == 1) ? bk : (z == 2) ? bv : (z == 3) ? nullptr : bo;

    const int bx = blockIdx.x;
    const int g  = bx >> 3, x8 = bx & 7;
    const int mtile = (g >> 2) * 8 + x8;   // 0..63
    const int ntile = g & 3;               // 0..3
    const int r0 = mtile * 128;
    const int c0 = ntile * 128;

    const int tid  = threadIdx.x;
    const int wave = tid >> 6;
    const int lane = tid & 63;
    const int quad = lane >> 4;
    const int l16  = lane & 15;
    const int rb = (wave >> 1) * 64;
    const int cb = (wave & 1) * 64;

    __shared__ __align__(16) float Xs[128][68];
    __shared__ float Wt[128][65];

    f32x4 acc[4][4];
#pragma unroll
    for (int mt = 0; mt < 4; mt++)
#pragma unroll
        for (int nt = 0; nt < 4; nt++)
#pragma unroll
            for (int r = 0; r < 4; r++) acc[mt][nt][r] = 0.f;

    for (int it = 0; it < 8; ++it) {
        const int k0 = it * 64;
#pragma unroll
        for (int rep = 0; rep < 8; rep++) {
            int id = rep * 256 + tid;
            int m = id >> 4, c = id & 15;
            f32x4 v = *(const f32x4*)&X[(size_t)(r0 + m) * 512 + k0 + c * 4];
            *(f32x4*)&Xs[m][c * 4] = v;
        }
#pragma unroll
        for (int rep = 0; rep < 8; rep++) {
            int id = rep * 256 + tid;
            int cc = id & 31, kk = id >> 5;
            f32x4 v = *(const f32x4*)&W[(size_t)(k0 + kk) * 512 + c0 + cc * 4];
#pragma unroll
            for (int i = 0; i < 4; i++) Wt[cc * 4 + i][kk] = v[i];
        }
        __syncthreads();

#pragma unroll
        for (int kc = 0; kc < 2; kc++) {
            bf16x8 Bhi[4], Blo[4];
#pragma unroll
            for (int nt = 0; nt < 4; nt++) {
#pragma unroll
                for (int e = 0; e < 8; e++) {
                    float f = Wt[cb + nt * 16 + l16][kc * 32 + quad * 8 + e];
                    bf16_t hi = (bf16_t)f;
                    Bhi[nt][e] = hi;
                    Blo[nt][e] = (bf16_t)(f - (float)hi);
                }
            }
#pragma unroll
            for (int mt = 0; mt < 4; mt++) {
                f32x4 a0 = *(const f32x4*)&Xs[rb + mt * 16 + l16][kc * 32 + quad * 8];
                f32x4 a1 = *(const f32x4*)&Xs[rb + mt * 16 + l16][kc * 32 + quad * 8 + 4];
                bf16x8 Ahi, Alo;
#pragma unroll
                for (int e = 0; e < 4; e++) {
                    bf16_t h0 = (bf16_t)a0[e];
                    Ahi[e] = h0; Alo[e] = (bf16_t)(a0[e] - (float)h0);
                    bf16_t h1 = (bf16_t)a1[e];
                    Ahi[4 + e] = h1; Alo[4 + e] = (bf16_t)(a1[e] - (float)h1);
                }
#pragma unroll
                for (int nt = 0; nt < 4; nt++) {
                    acc[mt][nt] = __builtin_amdgcn_mfma_f32_16x16x32_bf16(Ahi, Bhi[nt], acc[mt][nt], 0, 0, 0);
                    acc[mt][nt] = __builtin_amdgcn_mfma_f32_16x16x32_bf16(Ahi, Blo[nt], acc[mt][nt], 0, 0, 0);
                    acc[mt][nt] = __builtin_amdgcn_mfma_f32_16x16x32_bf16(Alo, Bhi[nt], acc[mt][nt], 0, 0, 0);
                }
            }
        }
        __syncthreads();
    }

#pragma unroll
    for (int mt = 0; mt < 4; mt++) {
#pragma unroll
        for (int r = 0; r < 4; r++) {
            int row = r0 + rb + mt * 16 + quad * 4 + r;
#pragma unroll
            for (int nt = 0; nt < 4; nt++) {
                int col = c0 + cb + nt * 16 + l16;
                float y = acc[mt][nt][r] + (bias ? bias[col] : 0.f);
                if (z == 4) {
                    OUT[(size_t)row * 512 + col] = y;
                } else {
                    int b = row >> 11, t = row & 2047;
                    int h = col >> 6,  d = col & 63;
                    if (z == 0) {
                        size_t idx = (((size_t)(b * Hh + h)) * Tt + t) * Dd + d;
                        QU[idx] = (bf16_t)(y + bias_u[col]);
                        QV[idx] = (bf16_t)(y + bias_v[col]);
                    } else if (z == 1) {
                        size_t idx = (((size_t)(b * Hh + h)) * Tt + t) * Dd + d;
                        K16[idx] = (bf16_t)y;
                    } else if (z == 2) {
                        // transposed: VT[bh][d][t]
                        size_t idx = (((size_t)(b * Hh + h)) * Dd + d) * Tt + t;
                        VT16[idx] = (bf16_t)y;
                    } else {
                        size_t idx = (((size_t)(b * Hh + h)) * Tt + t) * Dd + d;
                        P16[idx] = (bf16_t)y;
                    }
                }
            }
        }
    }
}

// ---------------------------------------------------------------------------
// Kernel 2: attention. grid = (bh=32, itile=32); same-bh blocks share an XCD.
// LDS map (bytes), total 38912:
//   [0,     18432)  pA  [128][72] bf16: P band rows 0..(w1+w2)
//   [18432, 27648)  k_s [64][72]
//   [27648, 38912)  msw [64][88] bf16, wave-private strips, STRIP-LOCAL
//                   skewed pos scores (col' = jl + 15 - (il - wave*16),
//                   window [0,78]); softmax weights later clobber cols 0..63
//                   (strictly after the gathers).
// Q A-frags + V B-frags (via VT[bh][d][t]) load direct from global.
// ---------------------------------------------------------------------------
__global__ __launch_bounds__(256, 3)
void attn_kernel(const bf16_t* __restrict__ QU, const bf16_t* __restrict__ QV,
                 const bf16_t* __restrict__ K16, const bf16_t* __restrict__ VT16,
                 const bf16_t* __restrict__ P16, float* __restrict__ CTX)
{
    const int bh = blockIdx.x;                 // XCD locality: linear%8 = bh%8
    const int i0 = blockIdx.y * 64;
    const int b = bh >> 3, h = bh & 7;
    const int tid = threadIdx.x;
    const int wave = tid >> 6;
    const int lane = tid & 63;
    const int quad = lane >> 4;
    const int l16 = lane & 15;

    const bf16_t* qu_g = QU + (size_t)bh * Tt * Dd;
    const bf16_t* qv_g = QV + (size_t)bh * Tt * Dd;
    const bf16_t* k_g  = K16 + (size_t)bh * Tt * Dd;
    const bf16_t* vt_g = VT16 + (size_t)bh * Dd * Tt;   // [d][t]
    const bf16_t* p_g  = P16 + (size_t)bh * Tt * Dd;

    __shared__ __align__(16) char smem[38912];
    bf16_t (*pA)[72]  = (bf16_t (*)[72])(smem);           // 128 rows (P band)
    bf16_t (*k_s)[72] = (bf16_t (*)[72])(smem + 18432);   // 64 rows
    bf16_t (*msw)[88] = (bf16_t (*)[88])(smem + 27648);   // 64 rows, strip-local

    const int off_w = 48 - wave * 16;          // strip-local = absolute - off_w
    const int cmin = 48 - wave * 16;           // absolute strip window
    const int cmax = 126 - wave * 16;

    // A-operand fragments, direct global loads: A[m=l16][k=quad*8+e]
    const int qrow = i0 + wave * 16 + l16;
    const int qrow2 = (qrow + 1 > Tt - 1) ? (Tt - 1) : (qrow + 1);  // clamped row never gathered
    bf16x8 aq[2], av1[2], av2[2];
#pragma unroll
    for (int kc = 0; kc < 2; kc++) {
        aq[kc]  = *(const bf16x8*)(qu_g + (size_t)qrow  * Dd + kc * 32 + quad * 8);
        av1[kc] = *(const bf16x8*)(qv_g + (size_t)qrow  * Dd + kc * 32 + quad * 8);
        av2[kc] = *(const bf16x8*)(qv_g + (size_t)qrow2 * Dd + kc * 32 + quad * 8);
    }

    float lsum[4];
    f32x4 accO[4];
#pragma unroll
    for (int r = 0; r < 4; r++) lsum[r] = 0.f;
#pragma unroll
    for (int dt = 0; dt < 4; dt++)
#pragma unroll
        for (int r = 0; r < 4; r++) accO[dt][r] = 0.f;

    for (int j0 = 0; j0 < Tt; j0 += 64) {
        int d_lo = i0 - (j0 + 63);
        int d_hi = i0 + 63 - j0;
        int w1 = 0, prow1 = 0;
        if (d_hi >= 0) {
            int b1 = d_lo > 0 ? d_lo : 0;
            w1 = d_hi - b1 + 1;
            prow1 = (Tt - 1) - d_hi;
        }
        int dmax2 = d_hi < -2 ? d_hi : -2;
        int w2 = 0, e_lo = 0;
        if (d_lo <= dmax2) {
            e_lo = -dmax2 - 2;
            int e_hi = -d_lo - 2;
            w2 = e_hi - e_lo + 1;
        }
        int c2_0 = d_hi + 2 + e_lo;
        int nct1 = (w1 + 15) >> 4;
        int nct2 = (w2 + 15) >> 4;

        // stage K tile (coalesced; 2-way LDS writes = free)
        for (int idx = tid; idx < 64 * 8; idx += 256) {
            int row = idx >> 3, seg = idx & 7;
            *(f32x4*)&k_s[row][seg * 8] = *(const f32x4*)(k_g + (size_t)(j0 + row) * Dd + seg * 8);
        }
        // stage P band rows [0, w1+w2)
        for (int idx = tid; idx < (w1 + w2) * 8; idx += 256) {
            int rr = idx >> 3, seg = idx & 7;
            int srcrow = (rr < w1) ? (prow1 + rr) : (e_lo + rr - w1);
            *(f32x4*)&pA[rr][seg * 8] = *(const f32x4*)(p_g + (size_t)srcrow * Dd + seg * 8);
        }
        __syncthreads();

        // content scores
        f32x4 accS[4];
#pragma unroll
        for (int nt = 0; nt < 4; nt++) {
            f32x4 acc = {0.f, 0.f, 0.f, 0.f};
#pragma unroll
            for (int kc = 0; kc < 2; kc++) {
                bf16x8 bk8 = *(const bf16x8*)&k_s[nt * 16 + l16][kc * 32 + quad * 8];
                acc = __builtin_amdgcn_mfma_f32_16x16x32_bf16(aq[kc], bk8, acc, 0, 0, 0);
            }
            accS[nt] = acc;
        }

        // banded pos matmul -> strip-local skewed store (wave-private)
        for (int ct = 0; ct < nct1 + nct2; ct++) {
            bool b2 = ct >= nct1;
            int rb_ = b2 ? (w1 + (ct - nct1) * 16) : (ct * 16);
            int cb_ = b2 ? (c2_0 + (ct - nct1) * 16) : (ct * 16);
            if (cb_ > cmax || cb_ + 15 < cmin) continue;
            f32x4 acc = {0.f, 0.f, 0.f, 0.f};
#pragma unroll
            for (int kc = 0; kc < 2; kc++) {
                bf16x8 bp = *(const bf16x8*)&pA[rb_ + l16][kc * 32 + quad * 8];
                acc = b2 ? __builtin_amdgcn_mfma_f32_16x16x32_bf16(av2[kc], bp, acc, 0, 0, 0)
                         : __builtin_amdgcn_mfma_f32_16x16x32_bf16(av1[kc], bp, acc, 0, 0, 0);
            }
            int colp = cb_ + l16 - off_w;          // strip-local
            if ((unsigned)colp < 80u) {
#pragma unroll
                for (int r = 0; r < 4; r++)
                    msw[wave * 16 + quad * 4 + r][colp] = (bf16_t)acc[r];
            }
        }
        // zero column for dd == -1 (strip-local)
        {
            int zcl = d_hi + 1 - off_w;
            if ((unsigned)zcl < 80u && quad == 0)
                msw[wave * 16 + l16][zcl] = (bf16_t)0.f;
        }

        // gather all 16 (no aliasing stores in between), then write weights
        float wv[4][4];
#pragma unroll
        for (int nt = 0; nt < 4; nt++) {
#pragma unroll
            for (int r = 0; r < 4; r++) {
                float pos = (float)msw[wave * 16 + quad * 4 + r]
                                    [nt * 16 + l16 + 15 - (quad * 4 + r)];
                float x = accS[nt][r] + pos;
                float a = fminf(fmaf(x, 0.18033688f, -17.3123405f), 120.0f);
                float w = exp2f(a);
                lsum[r] += w;
                wv[nt][r] = w;
            }
        }
#pragma unroll
        for (int nt = 0; nt < 4; nt++)
#pragma unroll
            for (int r = 0; r < 4; r++)
                msw[wave * 16 + quad * 4 + r][nt * 16 + l16] = (bf16_t)wv[nt][r];

        // O += W @ V : A from own msw strip, B direct from VT ([d][t])
#pragma unroll
        for (int kc = 0; kc < 2; kc++) {
            bf16x8 aw = *(const bf16x8*)&msw[wave * 16 + l16][kc * 32 + quad * 8];
#pragma unroll
            for (int dt = 0; dt < 4; dt++) {
                bf16x8 bv8 = *(const bf16x8*)(vt_g + (size_t)(dt * 16 + l16) * Tt + j0 + kc * 32 + quad * 8);
                accO[dt] = __builtin_amdgcn_mfma_f32_16x16x32_bf16(aw, bv8, accO[dt], 0, 0, 0);
            }
        }
        __syncthreads();  // protect k_s/pA before next staging
    }

#pragma unroll
    for (int r = 0; r < 4; r++) {
#pragma unroll
        for (int off = 1; off < 16; off <<= 1) lsum[r] += __shfl_xor(lsum[r], off, 64);
    }

#pragma unroll
    for (int r = 0; r < 4; r++) {
        int il = wave * 16 + quad * 4 + r;
        int ig = i0 + il;
        float inv = 1.0f / lsum[r];
#pragma unroll
        for (int dt = 0; dt < 4; dt++) {
            CTX[((size_t)(b * Tt + ig)) * Cc + h * Dd + dt * 16 + l16] = accO[dt][r] * inv;
        }
    }
}

// ---------------------------------------------------------------------------
extern "C" void kernel_launch(void* const* d_in, const int* in_sizes, int n_in,
                              void* d_out, int out_size, void* d_ws, size_t ws_size,
                              hipStream_t stream)
{
    const float* query = (const float*)d_in[0];
    const float* key   = (const float*)d_in[1];
    const float* value = (const float*)d_in[2];
    const float* pemb  = (const float*)d_in[3];
    const float* Wq    = (const float*)d_in[4];
    const float* bq    = (const float*)d_in[5];
    const float* Wk    = (const float*)d_in[6];
    const float* bk    = (const float*)d_in[7];
    const float* Wv    = (const float*)d_in[8];
    const float* bv    = (const float*)d_in[9];
    const float* Wpos  = (const float*)d_in[10];
    const float* pbu   = (const float*)d_in[11];
    const float* pbv   = (const float*)d_in[12];
    const float* Wo    = (const float*)d_in[13];
    const float* bo    = (const float*)d_in[14];

    const size_t NE = (size_t)Bb * Hh * Tt * Dd;  // 4,194,304 per tensor
    bf16_t* QU   = (bf16_t*)d_ws;
    bf16_t* QV   = QU + NE;
    bf16_t* K16  = QV + NE;
    bf16_t* VT16 = K16 + NE;
    bf16_t* P16  = VT16 + NE;
    float*  CTX  = (float*)(P16 + NE);            // ws >= 56 MB

    // QKVP projections (z = blockIdx.z)
    split_gemm_kernel<<<dim3(256, 1, 4), 256, 0, stream>>>(
        query, key, value, pemb, CTX, Wq, Wk, Wv, Wpos, Wo,
        bq, bk, bv, bo, pbu, pbv, QU, QV, K16, VT16, P16, (float*)d_out, -1);

    attn_kernel<<<dim3(32, 32), 256, 0, stream>>>(QU, QV, K16, VT16, P16, CTX);

    // output projection (mode 4)
    split_gemm_kernel<<<dim3(256, 1, 1), 256, 0, stream>>>(
        query, key, value, pemb, CTX, Wq, Wk, Wv, Wpos, Wo,
        bq, bk, bv, bo, pbu, pbv, QU, QV, K16, VT16, P16, (float*)d_out, 4);
}